// Round 4
// baseline (19412.944 us; speedup 1.0000x reference)
//
#include <hip/hip_runtime.h>
#include <hip/hip_cooperative_groups.h>
#include <math.h>

namespace cg = cooperative_groups;

typedef __bf16 bf16_t;
typedef __bf16 bf16x8 __attribute__((ext_vector_type(8)));
typedef float f32x4 __attribute__((ext_vector_type(4)));

#define SEG 2560   // 64 rows * 40 elems, one LDS [buf][half] segment

// ---------------------------------------------------------------------------
// GRU phase: C[256,4096] = A[256,K] @ W4[4096,K]^T + combine. 256 blocks x
// 8 waves (4 row-groups x 2 col-halves), 64x64 tile, BK=64, dbuf LDS,
// one barrier per BK. W4 row order n' = (c>>4)*64 + ((c>>3)&1)*32 + g*8 +
// (c&7); epilogue pairs gates via __shfl_xor(8). (verified in R3)
// ---------------------------------------------------------------------------
__device__ __forceinline__ void gru_phase(
    const bf16_t* __restrict__ A, const bf16_t* __restrict__ W,
    const float* __restrict__ bias, int K,
    float* __restrict__ hf,
    bf16_t* __restrict__ d1, int ld1, int off1,
    bf16_t* __restrict__ d2, int ld2, int off2,
    int bid, int tid, bf16_t* sAp, bf16_t* sBp)
{
    // XCD-aware remap: XCD x gets n-blocks [x*8, x*8+8)
    const int bx = (bid & 7) * 8 + ((bid >> 3) & 7);
    const int by = bid >> 6;
    const int bm = by * 64, bn = bx * 64;

    const int srow = tid >> 3, schk = tid & 7;
    const int shalf = schk >> 2;
    const unsigned so = srow * 40 + (schk & 3) * 8;
    const bf16_t* gA = A + (size_t)(bm + srow) * K + schk * 8;
    const bf16_t* gW = W + (size_t)(bn + srow) * K + schk * 8;

    const int lane = tid & 63, wv = tid >> 6;
    const int rg = wv >> 1, chh = wv & 1;
    const int quad = lane >> 4, col = lane & 15;
    const unsigned ra = (rg * 16 + col) * 40 + quad * 8;
    const unsigned rb = (chh * 32 + col) * 40 + quad * 8;

    f32x4 acc0, acc1;
#pragma unroll
    for (int e = 0; e < 4; e++) { acc0[e] = 0.f; acc1[e] = 0.f; }

    int4 pa, pb;
    pa = *(const int4*)gA; pb = *(const int4*)gW; gA += 64; gW += 64;
    *(int4*)&sAp[shalf * SEG + so] = pa;
    *(int4*)&sBp[shalf * SEG + so] = pb;
    pa = *(const int4*)gA; pb = *(const int4*)gW; gA += 64; gW += 64;

    const int nit = K >> 6;
    __syncthreads();

    for (int c = 0; c < nit; ++c) {
        const unsigned cb = (unsigned)(c & 1) * (2 * SEG);
        bf16x8 af0 = *(const bf16x8*)&sAp[cb + ra];
        bf16x8 af1 = *(const bf16x8*)&sAp[cb + SEG + ra];
        bf16x8 b00 = *(const bf16x8*)&sBp[cb + rb];
        bf16x8 b01 = *(const bf16x8*)&sBp[cb + rb + 16 * 40];
        bf16x8 b10 = *(const bf16x8*)&sBp[cb + SEG + rb];
        bf16x8 b11 = *(const bf16x8*)&sBp[cb + SEG + rb + 16 * 40];

        if (c + 1 < nit) {
            const unsigned nb = (unsigned)((c + 1) & 1) * (2 * SEG);
            *(int4*)&sAp[nb + shalf * SEG + so] = pa;
            *(int4*)&sBp[nb + shalf * SEG + so] = pb;
            if (c + 2 < nit) {
                pa = *(const int4*)gA; pb = *(const int4*)gW;
                gA += 64; gW += 64;
            }
        }

        acc0 = __builtin_amdgcn_mfma_f32_16x16x32_bf16(af0, b00, acc0, 0, 0, 0);
        acc1 = __builtin_amdgcn_mfma_f32_16x16x32_bf16(af0, b01, acc1, 0, 0, 0);
        acc0 = __builtin_amdgcn_mfma_f32_16x16x32_bf16(af1, b10, acc0, 0, 0, 0);
        acc1 = __builtin_amdgcn_mfma_f32_16x16x32_bf16(af1, b11, acc1, 0, 0, 0);

        __syncthreads();
    }

    const int cch = (bn >> 2) + chh * 8 + (col & 7);
    const float b0 = bias[bn + chh * 32 + col];
    const float b1 = bias[bn + chh * 32 + 16 + col];
#pragma unroll
    for (int r = 0; r < 4; r++) {
        const int m = bm + rg * 16 + quad * 4 + r;
        const float a0 = acc0[r] + b0;
        const float a1 = acc1[r] + b1;
        const float p0 = __shfl_xor(a0, 8, 64);
        const float p1 = __shfl_xor(a1, 8, 64);
        const float gr  = (col < 8) ? a0 : p0;
        const float gz  = (col < 8) ? p0 : a0;
        const float gin = (col < 8) ? a1 : p1;
        const float ghn = (col < 8) ? p1 : a1;
        const float rr = 1.f / (1.f + __expf(-gr));
        const float zz = 1.f / (1.f + __expf(-gz));
        const float nn = tanhf(gin + rr * ghn);
        if (col < 8) {
            const size_t hidx = (size_t)m * 1024 + cch;
            const float hnew = (1.f - zz) * nn + zz * hf[hidx];
            hf[hidx] = hnew;
            const bf16_t hb = (bf16_t)hnew;
            d1[(size_t)m * ld1 + off1 + cch] = hb;
            d2[(size_t)m * ld2 + off2 + cch] = hb;
        }
    }
}

// ---------------------------------------------------------------------------
// FC phase: C[M,N] = A[M,K] @ W[N,K]^T + bias. 32x64 tile, 2 active waves
// (tid<128); waves 2..7 execute barriers only. BK=64 dbuf, 1 barrier/BK.
// ---------------------------------------------------------------------------
__device__ __forceinline__ void fc_phase(
    const bf16_t* __restrict__ A, const bf16_t* __restrict__ W,
    const float* __restrict__ bias, int K,
    float* __restrict__ C, int ldc,
    int bx, int by, int tid, bf16_t* sAp, bf16_t* sBp)
{
    const bool act = tid < 128;
    const int bm = by * 32, bn = bx * 64;
    const int srow = tid >> 2, schk = tid & 3;
    const bf16_t* gA = A + (size_t)(bm + (srow & 31)) * K + schk * 8;
    const bf16_t* gW = W + (size_t)(bn + (srow & 31)) * K + schk * 8;
    const unsigned sa = (srow & 31) * 40 + schk * 8;

    const int lane = tid & 63, wv = tid >> 6;
    const int quad = lane >> 4, col = lane & 15;
    const unsigned ra = ((wv & 1) * 16 + col) * 40 + quad * 8;
    const unsigned rb = col * 40 + quad * 8;

    f32x4 acc[4];
#pragma unroll
    for (int j = 0; j < 4; j++)
#pragma unroll
        for (int e = 0; e < 4; e++) acc[j][e] = 0.f;

    int4 pa0{}, pa1{}, pb0[2], pb1[2];

    if (act) {
        pa0 = *(const int4*)gA;
        pa1 = *(const int4*)(gA + 32);
#pragma unroll
        for (int r = 0; r < 2; r++) {
            pb0[r] = *(const int4*)(gW + (size_t)(r * 32) * K);
            pb1[r] = *(const int4*)(gW + (size_t)(r * 32) * K + 32);
        }
        gA += 64; gW += 64;

        *(int4*)&sAp[sa] = pa0;
        *(int4*)&sAp[SEG + sa] = pa1;
#pragma unroll
        for (int r = 0; r < 2; r++) {
            *(int4*)&sBp[sa + r * 1280] = pb0[r];
            *(int4*)&sBp[SEG + sa + r * 1280] = pb1[r];
        }

        pa0 = *(const int4*)gA;
        pa1 = *(const int4*)(gA + 32);
#pragma unroll
        for (int r = 0; r < 2; r++) {
            pb0[r] = *(const int4*)(gW + (size_t)(r * 32) * K);
            pb1[r] = *(const int4*)(gW + (size_t)(r * 32) * K + 32);
        }
        gA += 64; gW += 64;
    }

    const int nit = K >> 6;
    __syncthreads();

    for (int c = 0; c < nit; ++c) {
        if (act) {
            const unsigned cb = (unsigned)(c & 1) * (2 * SEG);
            bf16x8 af0 = *(const bf16x8*)&sAp[cb + ra];
            bf16x8 af1 = *(const bf16x8*)&sAp[cb + SEG + ra];
            bf16x8 b00 = *(const bf16x8*)&sBp[cb + rb];
            bf16x8 b01 = *(const bf16x8*)&sBp[cb + rb + 16 * 40];
            bf16x8 b02 = *(const bf16x8*)&sBp[cb + rb + 32 * 40];
            bf16x8 b03 = *(const bf16x8*)&sBp[cb + rb + 48 * 40];
            bf16x8 b10 = *(const bf16x8*)&sBp[cb + SEG + rb];
            bf16x8 b11 = *(const bf16x8*)&sBp[cb + SEG + rb + 16 * 40];
            bf16x8 b12 = *(const bf16x8*)&sBp[cb + SEG + rb + 32 * 40];
            bf16x8 b13 = *(const bf16x8*)&sBp[cb + SEG + rb + 48 * 40];

            if (c + 1 < nit) {
                const unsigned nb = (unsigned)((c + 1) & 1) * (2 * SEG);
                *(int4*)&sAp[nb + sa] = pa0;
                *(int4*)&sAp[nb + SEG + sa] = pa1;
#pragma unroll
                for (int r = 0; r < 2; r++) {
                    *(int4*)&sBp[nb + sa + r * 1280] = pb0[r];
                    *(int4*)&sBp[nb + SEG + sa + r * 1280] = pb1[r];
                }
                if (c + 2 < nit) {
                    pa0 = *(const int4*)gA;
                    pa1 = *(const int4*)(gA + 32);
#pragma unroll
                    for (int r = 0; r < 2; r++) {
                        pb0[r] = *(const int4*)(gW + (size_t)(r * 32) * K);
                        pb1[r] = *(const int4*)(gW + (size_t)(r * 32) * K + 32);
                    }
                    gA += 64; gW += 64;
                }
            }

            acc[0] = __builtin_amdgcn_mfma_f32_16x16x32_bf16(af0, b00, acc[0], 0, 0, 0);
            acc[1] = __builtin_amdgcn_mfma_f32_16x16x32_bf16(af0, b01, acc[1], 0, 0, 0);
            acc[2] = __builtin_amdgcn_mfma_f32_16x16x32_bf16(af0, b02, acc[2], 0, 0, 0);
            acc[3] = __builtin_amdgcn_mfma_f32_16x16x32_bf16(af0, b03, acc[3], 0, 0, 0);
            acc[0] = __builtin_amdgcn_mfma_f32_16x16x32_bf16(af1, b10, acc[0], 0, 0, 0);
            acc[1] = __builtin_amdgcn_mfma_f32_16x16x32_bf16(af1, b11, acc[1], 0, 0, 0);
            acc[2] = __builtin_amdgcn_mfma_f32_16x16x32_bf16(af1, b12, acc[2], 0, 0, 0);
            acc[3] = __builtin_amdgcn_mfma_f32_16x16x32_bf16(af1, b13, acc[3], 0, 0, 0);
        }
        __syncthreads();
    }

    if (act) {
#pragma unroll
        for (int j = 0; j < 4; j++) {
            const int n = bn + j * 16 + col;
            const float bj = bias[n];
#pragma unroll
            for (int r = 0; r < 4; r++) {
                const int m = bm + (wv & 1) * 16 + quad * 4 + r;
                C[(size_t)m * ldc + n] = acc[j][r] + bj;
            }
        }
    }
}

// ---------------------------------------------------------------------------
// LayerNorm + exact GELU phase, 512 threads, one row per block.
// ---------------------------------------------------------------------------
template <int N>
__device__ __forceinline__ void ln_phase(
    const float* __restrict__ X, const float* __restrict__ gg,
    const float* __restrict__ bb, bf16_t* __restrict__ Y,
    int row, int tid, float* red)
{
    constexpr int PT = N / 512;
    float v[PT];
    float s = 0.f;
#pragma unroll
    for (int i = 0; i < PT; i++) {
        v[i] = X[(size_t)row * N + tid + i * 512];
        s += v[i];
    }
#pragma unroll
    for (int o = 32; o > 0; o >>= 1) s += __shfl_xor(s, o, 64);
    if ((tid & 63) == 0) red[tid >> 6] = s;
    __syncthreads();
    s = 0.f;
#pragma unroll
    for (int w = 0; w < 8; w++) s += red[w];
    __syncthreads();
    const float mu = s * (1.f / N);
    float s2 = 0.f;
#pragma unroll
    for (int i = 0; i < PT; i++) { float d = v[i] - mu; s2 += d * d; }
#pragma unroll
    for (int o = 32; o > 0; o >>= 1) s2 += __shfl_xor(s2, o, 64);
    if ((tid & 63) == 0) red[tid >> 6] = s2;
    __syncthreads();
    s2 = 0.f;
#pragma unroll
    for (int w = 0; w < 8; w++) s2 += red[w];
    __syncthreads();
    const float inv = rsqrtf(s2 * (1.f / N) + 1e-5f);
#pragma unroll
    for (int i = 0; i < PT; i++) {
        const int c = tid + i * 512;
        const float t = (v[i] - mu) * inv * gg[c] + bb[c];
        Y[(size_t)row * N + c] = (bf16_t)(0.5f * t * (1.f + erff(t * 0.70710678118654752f)));
    }
}

// ---------------------------------------------------------------------------
// softmax phase: one row per block, wave 0 only (no block barrier).
// ---------------------------------------------------------------------------
__device__ __forceinline__ void sm_phase(
    const float* __restrict__ logits, float* __restrict__ dout,
    bf16_t* __restrict__ a0w, int t, int row, int tid)
{
    if (tid >= 64) return;
    const int lane = tid;
    float v[4];
#pragma unroll
    for (int j = 0; j < 4; j++) v[j] = logits[(size_t)row * 256 + lane + 64 * j];
    float mx = fmaxf(fmaxf(v[0], v[1]), fmaxf(v[2], v[3]));
#pragma unroll
    for (int o = 32; o > 0; o >>= 1) mx = fmaxf(mx, __shfl_xor(mx, o, 64));
    float e[4], s = 0.f;
#pragma unroll
    for (int j = 0; j < 4; j++) { e[j] = expf(v[j] - mx); s += e[j]; }
#pragma unroll
    for (int o = 32; o > 0; o >>= 1) s += __shfl_xor(s, o, 64);
    const float inv = 1.f / s;
#pragma unroll
    for (int j = 0; j < 4; j++) {
        const float p = e[j] * inv;
        const int c = lane + 64 * j;
        dout[((size_t)row * 64 + t) * 256 + c] = p;
        a0w[(size_t)row * 1280 + c] = (bf16_t)p;
    }
}

// ---------------------------------------------------------------------------
// Persistent cooperative kernel: whole 64-step decode loop, grid syncs
// replacing kernel boundaries. 256 blocks x 512 threads, 1 block/CU.
// ---------------------------------------------------------------------------
struct PArgs {
    const bf16_t* W4_0; const float* b4_0;
    const bf16_t* W4_1; const float* b4_1;
    const bf16_t* fc1w; const float* fc1_b;
    const float* ln1_g; const float* ln1_b;
    const bf16_t* fc2w; const float* fc2_b;
    const float* ln2_g; const float* ln2_b;
    const bf16_t* fc3w; const float* fc3_b;
    float* h0f; float* h1f;
    bf16_t* A0a; bf16_t* A0b; bf16_t* A1a; bf16_t* A1b;
    bf16_t* h1b; float* a1r; bf16_t* a1bf; float* a2r; bf16_t* a2bf;
    float* logits; float* dout;
};

__global__ __launch_bounds__(512, 2) void persist(PArgs P)
{
    __shared__ __align__(16) bf16_t sA[4 * SEG];
    __shared__ __align__(16) bf16_t sB[4 * SEG];
    __shared__ float red[8];

    cg::grid_group grid = cg::this_grid();
    const int bid = blockIdx.x, tid = threadIdx.x;

    for (int t = 0; t < 64; ++t) {
        bf16_t* A0r = (t & 1) ? P.A0b : P.A0a;
        bf16_t* A0w = (t & 1) ? P.A0a : P.A0b;
        bf16_t* A1r = (t & 1) ? P.A1b : P.A1a;
        bf16_t* A1w = (t & 1) ? P.A1a : P.A1b;

        // GRU layer 0: reads A0r=[out|h0]; writes h0 -> A1r[:, :1024] and
        // A0w[:, 256:1280], updates h0f.
        gru_phase(A0r, P.W4_0, P.b4_0, 1280, P.h0f,
                  A1r, 2048, 0, A0w, 1280, 256, bid, tid, sA, sB);
        grid.sync();
        // GRU layer 1: reads A1r=[h0_new|h1_old]; writes h1 -> A1w[:, 1024:]
        // and h1b, updates h1f.
        gru_phase(A1r, P.W4_1, P.b4_1, 2048, P.h1f,
                  A1w, 2048, 1024, P.h1b, 1024, 0, bid, tid, sA, sB);
        grid.sync();
        // FC1: [256,1024] = h1b @ fc1^T   (128 tiles of 32x64)
        if (bid < 128)
            fc_phase(P.h1b, P.fc1w, P.fc1_b, 1024, P.a1r, 1024,
                     bid & 15, bid >> 4, tid, sA, sB);
        grid.sync();
        ln_phase<1024>(P.a1r, P.ln1_g, P.ln1_b, P.a1bf, bid, tid, red);
        grid.sync();
        // FC2: [256,512]   (64 tiles)
        if (bid < 64)
            fc_phase(P.a1bf, P.fc2w, P.fc2_b, 1024, P.a2r, 512,
                     bid & 7, bid >> 3, tid, sA, sB);
        grid.sync();
        ln_phase<512>(P.a2r, P.ln2_g, P.ln2_b, P.a2bf, bid, tid, red);
        grid.sync();
        // FC3: [256,256]   (32 tiles)
        if (bid < 32)
            fc_phase(P.a2bf, P.fc3w, P.fc3_b, 512, P.logits, 256,
                     bid & 3, bid >> 2, tid, sA, sB);
        grid.sync();
        sm_phase(P.logits, P.dout, A0w, t, bid, tid);
        grid.sync();
    }
}

// ---------------------------------------------------------------------------
// Weight prep (unchanged from R3)
// ---------------------------------------------------------------------------
__global__ __launch_bounds__(256) void build_w4(
    const float* __restrict__ Wih, const float* __restrict__ Whh,
    const float* __restrict__ bih, const float* __restrict__ bhh,
    bf16_t* __restrict__ W4, float* __restrict__ b4, int Kx)
{
    const int K = Kx + 1024;
    const int tpr = K >> 2;
    const int idx = blockIdx.x * 256 + threadIdx.x;
    const int np = idx / tpr;
    const int k4 = (idx - np * tpr) * 4;
    const int lo = np & 7;
    const int g = (np >> 3) & 3;
    const int hi = (np >> 5) & 1;
    const int c = ((np >> 6) << 4) + (hi << 3) + lo;
    const int srow = (g == 0 ? c : (g == 1 ? 1024 + c : 2048 + c));
    float4 v = make_float4(0.f, 0.f, 0.f, 0.f);
    if (k4 < Kx) {
        if (g != 3) v = *(const float4*)(Wih + (size_t)srow * Kx + k4);
    } else {
        if (g != 2) v = *(const float4*)(Whh + (size_t)srow * 1024 + (k4 - Kx));
    }
    bf16_t* dst = W4 + (size_t)np * K + k4;
    dst[0] = (bf16_t)v.x; dst[1] = (bf16_t)v.y;
    dst[2] = (bf16_t)v.z; dst[3] = (bf16_t)v.w;
    if (k4 == 0) {
        b4[np] = (g == 0) ? bih[c] + bhh[c]
               : (g == 1) ? bih[1024 + c] + bhh[1024 + c]
               : (g == 2) ? bih[2048 + c] : bhh[2048 + c];
    }
}

__global__ __launch_bounds__(256) void conv_bf16(
    const float* __restrict__ src, bf16_t* __restrict__ dst)
{
    const int i4 = (blockIdx.x * 256 + threadIdx.x) * 4;
    float4 v = *(const float4*)(src + i4);
    dst[i4 + 0] = (bf16_t)v.x; dst[i4 + 1] = (bf16_t)v.y;
    dst[i4 + 2] = (bf16_t)v.z; dst[i4 + 3] = (bf16_t)v.w;
}

__global__ __launch_bounds__(256) void init_state(
    const float* __restrict__ hidden, float* __restrict__ h0f,
    float* __restrict__ h1f, bf16_t* __restrict__ A0_0, bf16_t* __restrict__ A1_0)
{
    const int i = blockIdx.x * 256 + threadIdx.x;
    const int m = i >> 10, c = i & 1023;
    const float h0 = hidden[i], h1 = hidden[262144 + i];
    h0f[i] = h0; h1f[i] = h1;
    A0_0[(size_t)m * 1280 + 256 + c] = (bf16_t)h0;
    A1_0[(size_t)m * 2048 + 1024 + c] = (bf16_t)h1;
    if (c < 256) A0_0[(size_t)m * 1280 + c] = (bf16_t)0.f;
}

extern "C" void kernel_launch(void* const* d_in, const int* in_sizes, int n_in,
                              void* d_out, int out_size, void* d_ws, size_t ws_size,
                              hipStream_t stream)
{
    const float* hidden = (const float*)d_in[0];
    const float* W_ih0  = (const float*)d_in[1];
    const float* W_hh0  = (const float*)d_in[2];
    const float* b_ih0  = (const float*)d_in[3];
    const float* b_hh0  = (const float*)d_in[4];
    const float* W_ih1  = (const float*)d_in[5];
    const float* W_hh1  = (const float*)d_in[6];
    const float* b_ih1  = (const float*)d_in[7];
    const float* b_hh1  = (const float*)d_in[8];
    const float* fc1_w  = (const float*)d_in[9];
    const float* fc1_b  = (const float*)d_in[10];
    const float* ln1_g  = (const float*)d_in[11];
    const float* ln1_b  = (const float*)d_in[12];
    const float* fc2_w  = (const float*)d_in[13];
    const float* fc2_b  = (const float*)d_in[14];
    const float* ln2_g  = (const float*)d_in[15];
    const float* ln2_b  = (const float*)d_in[16];
    const float* fc3_w  = (const float*)d_in[17];
    const float* fc3_b  = (const float*)d_in[18];
    float* dout = (float*)d_out;

    char* p = (char*)d_ws;
    auto alloc = [&](size_t bytes) { void* r = (void*)p; p += (bytes + 255) & ~(size_t)255; return r; };
    float*  h0f   = (float*)alloc(262144 * 4);
    float*  h1f   = (float*)alloc(262144 * 4);
    bf16_t* A0a   = (bf16_t*)alloc(256 * 1280 * 2);
    bf16_t* A0b   = (bf16_t*)alloc(256 * 1280 * 2);
    bf16_t* A1a   = (bf16_t*)alloc(256 * 2048 * 2);
    bf16_t* A1b   = (bf16_t*)alloc(256 * 2048 * 2);
    bf16_t* h1b   = (bf16_t*)alloc(262144 * 2);
    float*  a1r   = (float*)alloc(262144 * 4);
    bf16_t* a1bf  = (bf16_t*)alloc(262144 * 2);
    float*  a2r   = (float*)alloc(131072 * 4);
    bf16_t* a2bf  = (bf16_t*)alloc(131072 * 2);
    float*  logits= (float*)alloc(65536 * 4);
    float*  b4_0  = (float*)alloc(4096 * 4);
    float*  b4_1  = (float*)alloc(4096 * 4);
    bf16_t* W4_0  = (bf16_t*)alloc((size_t)4096 * 1280 * 2);
    bf16_t* W4_1  = (bf16_t*)alloc((size_t)4096 * 2048 * 2);
    bf16_t* fc1wb = (bf16_t*)alloc((size_t)1048576 * 2);
    bf16_t* fc2wb = (bf16_t*)alloc((size_t)524288 * 2);
    bf16_t* fc3wb = (bf16_t*)alloc((size_t)131072 * 2);

    // weight prep (runs every launch; ~40us total, graph-safe)
    build_w4<<<5120, 256, 0, stream>>>(W_ih0, W_hh0, b_ih0, b_hh0, W4_0, b4_0, 256);
    build_w4<<<8192, 256, 0, stream>>>(W_ih1, W_hh1, b_ih1, b_hh1, W4_1, b4_1, 1024);
    conv_bf16<<<1024, 256, 0, stream>>>(fc1_w, fc1wb);
    conv_bf16<<<512, 256, 0, stream>>>(fc2_w, fc2wb);
    conv_bf16<<<128, 256, 0, stream>>>(fc3_w, fc3wb);
    init_state<<<1024, 256, 0, stream>>>(hidden, h0f, h1f, A0a, A1a);

    PArgs pa;
    pa.W4_0 = W4_0; pa.b4_0 = b4_0;
    pa.W4_1 = W4_1; pa.b4_1 = b4_1;
    pa.fc1w = fc1wb; pa.fc1_b = fc1_b; pa.ln1_g = ln1_g; pa.ln1_b = ln1_b;
    pa.fc2w = fc2wb; pa.fc2_b = fc2_b; pa.ln2_g = ln2_g; pa.ln2_b = ln2_b;
    pa.fc3w = fc3wb; pa.fc3_b = fc3_b;
    pa.h0f = h0f; pa.h1f = h1f;
    pa.A0a = A0a; pa.A0b = A0b; pa.A1a = A1a; pa.A1b = A1b;
    pa.h1b = h1b; pa.a1r = a1r; pa.a1bf = a1bf; pa.a2r = a2r; pa.a2bf = a2bf;
    pa.logits = logits; pa.dout = dout;

    void* kp[] = { (void*)&pa };
    hipLaunchCooperativeKernel((const void*)persist, dim3(256), dim3(512),
                               kp, 0, stream);
}

// Round 5
// 4949.868 us; speedup vs baseline: 3.9219x; 3.9219x over previous
//
#include <hip/hip_runtime.h>
#include <math.h>

typedef __bf16 bf16_t;
typedef __bf16 bf16x8 __attribute__((ext_vector_type(8)));
typedef float f32x4 __attribute__((ext_vector_type(4)));

// ---------------------------------------------------------------------------
// GRU fused GEMM+combine. C[256,4096] = A[256,K] @ W4[4096,K]^T, K=1280|2048.
// Block: 64 rows x 64 cols, 4 waves (2 row-groups x 2 col-halves), each wave
// computes a 32x32 sub-tile (2x2 16x16 frags) -> LDS frag reads cut 48->32KB
// per BK=64 iter vs the 8-wave R3 layout. Grid (64,4) = 256 blocks.
// W4 row order n' = (c>>4)*64 + ((c>>3)&1)*32 + g*8 + (c&7): each 32-col half
// holds 8 channels x 4 gates {r,z,i_n,h_n}; epilogue pairs lanes via
// __shfl_xor(8).  BK=64, double-buffered LDS, one barrier per BK.
// ---------------------------------------------------------------------------
__global__ __launch_bounds__(256) void gru_gemm(
    const bf16_t* __restrict__ A, const bf16_t* __restrict__ W,
    const float* __restrict__ bias, int K,
    float* __restrict__ hf,
    bf16_t* __restrict__ d1, int ld1, int off1,
    bf16_t* __restrict__ d2, int ld2, int off2)
{
    __shared__ __align__(16) bf16_t ldsA[2][2][64 * 40];
    __shared__ __align__(16) bf16_t ldsB[2][2][64 * 40];

    int bx = blockIdx.x, by = blockIdx.y;
    {   // XCD-aware remap: XCD x gets n-blocks [x*8, x*8+8) (W slice ~2MB, L2-resident)
        int d = by * 64 + bx;
        bx = (d & 7) * 8 + ((d >> 3) & 7);
        by = d >> 6;
    }
    const int bm = by * 64, bn = bx * 64;
    const int tid = threadIdx.x;

    // staging: 256 threads; thread -> (row tid>>2, 32B chunk tid&3) of both A,W.
    // chunk c covers elems c*16 .. c*16+15 = half (c>>1), slots (c&1)*2, +1.
    const int srow = tid >> 2, schk = tid & 3;
    const int shalf = schk >> 1;
    const unsigned so = srow * 40 + (schk & 1) * 16;   // elem offset in half
    const bf16_t* gA = A + (size_t)(bm + srow) * K + schk * 16;
    const bf16_t* gW = W + (size_t)(bn + srow) * K + schk * 16;

    const int lane = tid & 63, wv = tid >> 6;
    const int rg = wv >> 1, chh = wv & 1;           // row-group(32), col-half(32)
    const int quad = lane >> 4, col = lane & 15;
    const unsigned ra = (rg * 32 + col) * 40 + quad * 8;       // +i*16*40
    const unsigned rb = (chh * 32 + col) * 40 + quad * 8;      // +j*16*40

    f32x4 acc[2][2];
#pragma unroll
    for (int i = 0; i < 2; i++)
#pragma unroll
        for (int j = 0; j < 2; j++)
#pragma unroll
            for (int e = 0; e < 4; e++) acc[i][j][e] = 0.f;

    int4 pa0, pa1, pb0, pb1;
    pa0 = *(const int4*)gA; pa1 = *(const int4*)(gA + 8);
    pb0 = *(const int4*)gW; pb1 = *(const int4*)(gW + 8);
    gA += 64; gW += 64;
    *(int4*)&ldsA[0][shalf][so] = pa0;
    *(int4*)&ldsA[0][shalf][so + 8] = pa1;
    *(int4*)&ldsB[0][shalf][so] = pb0;
    *(int4*)&ldsB[0][shalf][so + 8] = pb1;
    pa0 = *(const int4*)gA; pa1 = *(const int4*)(gA + 8);
    pb0 = *(const int4*)gW; pb1 = *(const int4*)(gW + 8);
    gA += 64; gW += 64;

    const int nit = K >> 6;
    __syncthreads();

    for (int c = 0; c < nit; ++c) {
        const int cur = c & 1;
        bf16x8 a00 = *(const bf16x8*)&ldsA[cur][0][ra];
        bf16x8 a01 = *(const bf16x8*)&ldsA[cur][0][ra + 16 * 40];
        bf16x8 a10 = *(const bf16x8*)&ldsA[cur][1][ra];
        bf16x8 a11 = *(const bf16x8*)&ldsA[cur][1][ra + 16 * 40];
        bf16x8 b00 = *(const bf16x8*)&ldsB[cur][0][rb];
        bf16x8 b01 = *(const bf16x8*)&ldsB[cur][0][rb + 16 * 40];
        bf16x8 b10 = *(const bf16x8*)&ldsB[cur][1][rb];
        bf16x8 b11 = *(const bf16x8*)&ldsB[cur][1][rb + 16 * 40];

        if (c + 1 < nit) {
            const int nxt = cur ^ 1;
            *(int4*)&ldsA[nxt][shalf][so] = pa0;
            *(int4*)&ldsA[nxt][shalf][so + 8] = pa1;
            *(int4*)&ldsB[nxt][shalf][so] = pb0;
            *(int4*)&ldsB[nxt][shalf][so + 8] = pb1;
            if (c + 2 < nit) {
                pa0 = *(const int4*)gA; pa1 = *(const int4*)(gA + 8);
                pb0 = *(const int4*)gW; pb1 = *(const int4*)(gW + 8);
                gA += 64; gW += 64;
            }
        }

        // K-chunk 0
        acc[0][0] = __builtin_amdgcn_mfma_f32_16x16x32_bf16(a00, b00, acc[0][0], 0, 0, 0);
        acc[0][1] = __builtin_amdgcn_mfma_f32_16x16x32_bf16(a00, b01, acc[0][1], 0, 0, 0);
        acc[1][0] = __builtin_amdgcn_mfma_f32_16x16x32_bf16(a01, b00, acc[1][0], 0, 0, 0);
        acc[1][1] = __builtin_amdgcn_mfma_f32_16x16x32_bf16(a01, b01, acc[1][1], 0, 0, 0);
        // K-chunk 1
        acc[0][0] = __builtin_amdgcn_mfma_f32_16x16x32_bf16(a10, b10, acc[0][0], 0, 0, 0);
        acc[0][1] = __builtin_amdgcn_mfma_f32_16x16x32_bf16(a10, b11, acc[0][1], 0, 0, 0);
        acc[1][0] = __builtin_amdgcn_mfma_f32_16x16x32_bf16(a11, b10, acc[1][0], 0, 0, 0);
        acc[1][1] = __builtin_amdgcn_mfma_f32_16x16x32_bf16(a11, b11, acc[1][1], 0, 0, 0);

        __syncthreads();
    }

    // epilogue: col-frag j=0 -> gates r|z, j=1 -> i_n|h_n. Lane pair
    // (col, col^8) exchange so both see all 4 gates of channel
    // cch = (bn>>2) + chh*8 + (col&7). Stores gated to col<8.
    const int cch = (bn >> 2) + chh * 8 + (col & 7);
    const float b0 = bias[bn + chh * 32 + col];
    const float b1 = bias[bn + chh * 32 + 16 + col];
#pragma unroll
    for (int i = 0; i < 2; i++) {
#pragma unroll
        for (int r = 0; r < 4; r++) {
            const int m = bm + rg * 32 + i * 16 + quad * 4 + r;
            const float a0 = acc[i][0][r] + b0;
            const float a1 = acc[i][1][r] + b1;
            const float p0 = __shfl_xor(a0, 8, 64);
            const float p1 = __shfl_xor(a1, 8, 64);
            const float gr  = (col < 8) ? a0 : p0;
            const float gz  = (col < 8) ? p0 : a0;
            const float gin = (col < 8) ? a1 : p1;
            const float ghn = (col < 8) ? p1 : a1;
            const float rr = 1.f / (1.f + __expf(-gr));
            const float zz = 1.f / (1.f + __expf(-gz));
            const float nn = tanhf(gin + rr * ghn);
            if (col < 8) {
                const size_t hidx = (size_t)m * 1024 + cch;
                const float hnew = (1.f - zz) * nn + zz * hf[hidx];
                hf[hidx] = hnew;
                const bf16_t hb = (bf16_t)hnew;
                d1[(size_t)m * ld1 + off1 + cch] = hb;
                d2[(size_t)m * ld2 + off2 + cch] = hb;
            }
        }
    }
}

// ---------------------------------------------------------------------------
// Generic MFMA GEMM (FC head): C[M,N] = A[M,K](bf16) @ W[N,K](bf16)^T + bias.
// Tile: (NW*16) x 64, BK=64, double-buffered LDS, one barrier per BK.
// ---------------------------------------------------------------------------
template<int NW>
__global__ __launch_bounds__(NW * 64) void gemm_mfma(
    const bf16_t* __restrict__ A, const bf16_t* __restrict__ W,
    const float* __restrict__ bias, int K,
    float* __restrict__ C, int ldc)
{
    constexpr int MT = NW * 16;
    constexpr int R = 4 / NW;
    __shared__ __align__(16) bf16_t ldsA[2][2][MT * 40];
    __shared__ __align__(16) bf16_t ldsB[2][2][64 * 40];

    const int bm = blockIdx.y * MT, bn = blockIdx.x * 64;
    const int tid = threadIdx.x;

    const int srow = tid >> 2, schk = tid & 3;
    const bf16_t* gA = A + (size_t)(bm + srow) * K + schk * 8;
    const bf16_t* gW = W + (size_t)(bn + srow) * K + schk * 8;
    const unsigned sa = srow * 40 + schk * 8;

    const int lane = tid & 63, wv = tid >> 6;
    const int quad = lane >> 4, col = lane & 15;
    const unsigned ra_off = (wv * 16 + col) * 40 + quad * 8;
    const unsigned rb_off = col * 40 + quad * 8;

    f32x4 acc[4];
#pragma unroll
    for (int j = 0; j < 4; j++)
#pragma unroll
        for (int e = 0; e < 4; e++) acc[j][e] = 0.f;

    int4 pa0, pa1, pb0[R], pb1[R];

    pa0 = *(const int4*)gA;
    pa1 = *(const int4*)(gA + 32);
#pragma unroll
    for (int r = 0; r < R; r++) {
        pb0[r] = *(const int4*)(gW + (size_t)(r * MT) * K);
        pb1[r] = *(const int4*)(gW + (size_t)(r * MT) * K + 32);
    }
    gA += 64; gW += 64;

    *(int4*)&ldsA[0][0][sa] = pa0;
    *(int4*)&ldsA[0][1][sa] = pa1;
#pragma unroll
    for (int r = 0; r < R; r++) {
        *(int4*)&ldsB[0][0][sa + r * MT * 40] = pb0[r];
        *(int4*)&ldsB[0][1][sa + r * MT * 40] = pb1[r];
    }

    pa0 = *(const int4*)gA;
    pa1 = *(const int4*)(gA + 32);
#pragma unroll
    for (int r = 0; r < R; r++) {
        pb0[r] = *(const int4*)(gW + (size_t)(r * MT) * K);
        pb1[r] = *(const int4*)(gW + (size_t)(r * MT) * K + 32);
    }
    gA += 64; gW += 64;

    const int nit = K >> 6;
    __syncthreads();

    for (int c = 0; c < nit; ++c) {
        const int cur = c & 1;
        bf16x8 af0 = *(const bf16x8*)&ldsA[cur][0][ra_off];
        bf16x8 af1 = *(const bf16x8*)&ldsA[cur][1][ra_off];
        bf16x8 b00 = *(const bf16x8*)&ldsB[cur][0][rb_off];
        bf16x8 b01 = *(const bf16x8*)&ldsB[cur][0][rb_off + 16 * 40];
        bf16x8 b02 = *(const bf16x8*)&ldsB[cur][0][rb_off + 32 * 40];
        bf16x8 b03 = *(const bf16x8*)&ldsB[cur][0][rb_off + 48 * 40];
        bf16x8 b10 = *(const bf16x8*)&ldsB[cur][1][rb_off];
        bf16x8 b11 = *(const bf16x8*)&ldsB[cur][1][rb_off + 16 * 40];
        bf16x8 b12 = *(const bf16x8*)&ldsB[cur][1][rb_off + 32 * 40];
        bf16x8 b13 = *(const bf16x8*)&ldsB[cur][1][rb_off + 48 * 40];

        if (c + 1 < nit) {
            const int nxt = cur ^ 1;
            *(int4*)&ldsA[nxt][0][sa] = pa0;
            *(int4*)&ldsA[nxt][1][sa] = pa1;
#pragma unroll
            for (int r = 0; r < R; r++) {
                *(int4*)&ldsB[nxt][0][sa + r * MT * 40] = pb0[r];
                *(int4*)&ldsB[nxt][1][sa + r * MT * 40] = pb1[r];
            }
            if (c + 2 < nit) {
                pa0 = *(const int4*)gA;
                pa1 = *(const int4*)(gA + 32);
#pragma unroll
                for (int r = 0; r < R; r++) {
                    pb0[r] = *(const int4*)(gW + (size_t)(r * MT) * K);
                    pb1[r] = *(const int4*)(gW + (size_t)(r * MT) * K + 32);
                }
                gA += 64; gW += 64;
            }
        }

        acc[0] = __builtin_amdgcn_mfma_f32_16x16x32_bf16(af0, b00, acc[0], 0, 0, 0);
        acc[1] = __builtin_amdgcn_mfma_f32_16x16x32_bf16(af0, b01, acc[1], 0, 0, 0);
        acc[2] = __builtin_amdgcn_mfma_f32_16x16x32_bf16(af0, b02, acc[2], 0, 0, 0);
        acc[3] = __builtin_amdgcn_mfma_f32_16x16x32_bf16(af0, b03, acc[3], 0, 0, 0);
        acc[0] = __builtin_amdgcn_mfma_f32_16x16x32_bf16(af1, b10, acc[0], 0, 0, 0);
        acc[1] = __builtin_amdgcn_mfma_f32_16x16x32_bf16(af1, b11, acc[1], 0, 0, 0);
        acc[2] = __builtin_amdgcn_mfma_f32_16x16x32_bf16(af1, b12, acc[2], 0, 0, 0);
        acc[3] = __builtin_amdgcn_mfma_f32_16x16x32_bf16(af1, b13, acc[3], 0, 0, 0);

        __syncthreads();
    }

#pragma unroll
    for (int j = 0; j < 4; j++) {
        const int n = bn + j * 16 + col;
        const float bj = bias[n];
#pragma unroll
        for (int r = 0; r < 4; r++) {
            const int m = bm + wv * 16 + quad * 4 + r;
            C[(size_t)m * ldc + n] = acc[j][r] + bj;
        }
    }
}

// ---------------------------------------------------------------------------
// Build fused GRU weight matrix W4[4096, K] (K = Kx + 1024), bf16, row order
// n' = (c>>4)*64 + ((c>>3)&1)*32 + g*8 + (c&7); g: 0=r, 1=z, 2=i_n (x only),
// 3=h_n (h only). Also builds fused bias b4.
// ---------------------------------------------------------------------------
__global__ __launch_bounds__(256) void build_w4(
    const float* __restrict__ Wih, const float* __restrict__ Whh,
    const float* __restrict__ bih, const float* __restrict__ bhh,
    bf16_t* __restrict__ W4, float* __restrict__ b4, int Kx)
{
    const int K = Kx + 1024;
    const int tpr = K >> 2;
    const int idx = blockIdx.x * 256 + threadIdx.x;   // over 4096*tpr, exact
    const int np = idx / tpr;
    const int k4 = (idx - np * tpr) * 4;
    const int lo = np & 7;
    const int g = (np >> 3) & 3;
    const int hi = (np >> 5) & 1;
    const int c = ((np >> 6) << 4) + (hi << 3) + lo;
    const int srow = (g == 0 ? c : (g == 1 ? 1024 + c : 2048 + c));
    float4 v = make_float4(0.f, 0.f, 0.f, 0.f);
    if (k4 < Kx) {
        if (g != 3) v = *(const float4*)(Wih + (size_t)srow * Kx + k4);
    } else {
        if (g != 2) v = *(const float4*)(Whh + (size_t)srow * 1024 + (k4 - Kx));
    }
    bf16_t* dst = W4 + (size_t)np * K + k4;
    dst[0] = (bf16_t)v.x; dst[1] = (bf16_t)v.y;
    dst[2] = (bf16_t)v.z; dst[3] = (bf16_t)v.w;
    if (k4 == 0) {
        b4[np] = (g == 0) ? bih[c] + bhh[c]
               : (g == 1) ? bih[1024 + c] + bhh[1024 + c]
               : (g == 2) ? bih[2048 + c] : bhh[2048 + c];
    }
}

// fp32 -> bf16 convert (4 elems/thread, exact grid)
__global__ __launch_bounds__(256) void conv_bf16(
    const float* __restrict__ src, bf16_t* __restrict__ dst)
{
    const int i4 = (blockIdx.x * 256 + threadIdx.x) * 4;
    float4 v = *(const float4*)(src + i4);
    dst[i4 + 0] = (bf16_t)v.x; dst[i4 + 1] = (bf16_t)v.y;
    dst[i4 + 2] = (bf16_t)v.z; dst[i4 + 3] = (bf16_t)v.w;
}

// ---------------------------------------------------------------------------
// init: h0f/h1f fp32 state, A0[0] = [bf16(0) | bf16(h0)], A1[0][:,1024:] = bf16(h1)
// ---------------------------------------------------------------------------
__global__ __launch_bounds__(256) void init_state(
    const float* __restrict__ hidden, float* __restrict__ h0f,
    float* __restrict__ h1f, bf16_t* __restrict__ A0_0, bf16_t* __restrict__ A1_0)
{
    const int i = blockIdx.x * 256 + threadIdx.x;   // over 262144
    const int m = i >> 10, c = i & 1023;
    const float h0 = hidden[i], h1 = hidden[262144 + i];
    h0f[i] = h0; h1f[i] = h1;
    A0_0[(size_t)m * 1280 + 256 + c] = (bf16_t)h0;
    A1_0[(size_t)m * 2048 + 1024 + c] = (bf16_t)h1;
    if (c < 256) A0_0[(size_t)m * 1280 + c] = (bf16_t)0.f;
}

// ---------------------------------------------------------------------------
// LayerNorm + exact GELU, bf16 output. One row per 256-thread block.
// ---------------------------------------------------------------------------
__device__ __forceinline__ float block_reduce_sum(float v, float* red)
{
#pragma unroll
    for (int o = 32; o > 0; o >>= 1) v += __shfl_xor(v, o, 64);
    const int wid = threadIdx.x >> 6;
    if ((threadIdx.x & 63) == 0) red[wid] = v;
    __syncthreads();
    float s = red[0] + red[1] + red[2] + red[3];
    __syncthreads();
    return s;
}

template <int N>
__global__ __launch_bounds__(256) void ln_gelu(
    const float* __restrict__ X, const float* __restrict__ g,
    const float* __restrict__ b, bf16_t* __restrict__ Y)
{
    __shared__ float red[4];
    const int row = blockIdx.x;
    const int tid = threadIdx.x;
    constexpr int PT = N / 256;
    float v[PT];
    float s = 0.f;
#pragma unroll
    for (int i = 0; i < PT; i++) {
        v[i] = X[(size_t)row * N + tid + i * 256];
        s += v[i];
    }
    const float mu = block_reduce_sum(s, red) * (1.f / N);
    float s2 = 0.f;
#pragma unroll
    for (int i = 0; i < PT; i++) { float d = v[i] - mu; s2 += d * d; }
    const float var = block_reduce_sum(s2, red) * (1.f / N);
    const float inv = rsqrtf(var + 1e-5f);
#pragma unroll
    for (int i = 0; i < PT; i++) {
        const int c = tid + i * 256;
        const float t = (v[i] - mu) * inv * g[c] + b[c];
        Y[(size_t)row * N + c] = (bf16_t)(0.5f * t * (1.f + erff(t * 0.70710678118654752f)));
    }
}

// ---------------------------------------------------------------------------
// softmax over logits rows; writes dout[b,t,:] fp32 and feedback bf16 into A0
// ---------------------------------------------------------------------------
__global__ __launch_bounds__(256) void softmax_fb(
    const float* __restrict__ logits, float* __restrict__ dout,
    bf16_t* __restrict__ a0w, int t)
{
    const int wv = threadIdx.x >> 6, lane = threadIdx.x & 63;
    const int row = blockIdx.x * 4 + wv;
    float v[4];
#pragma unroll
    for (int j = 0; j < 4; j++) v[j] = logits[(size_t)row * 256 + lane + 64 * j];
    float mx = fmaxf(fmaxf(v[0], v[1]), fmaxf(v[2], v[3]));
#pragma unroll
    for (int o = 32; o > 0; o >>= 1) mx = fmaxf(mx, __shfl_xor(mx, o, 64));
    float e[4], s = 0.f;
#pragma unroll
    for (int j = 0; j < 4; j++) { e[j] = expf(v[j] - mx); s += e[j]; }
#pragma unroll
    for (int o = 32; o > 0; o >>= 1) s += __shfl_xor(s, o, 64);
    const float inv = 1.f / s;
#pragma unroll
    for (int j = 0; j < 4; j++) {
        const float p = e[j] * inv;
        const int c = lane + 64 * j;
        dout[((size_t)row * 64 + t) * 256 + c] = p;
        a0w[(size_t)row * 1280 + c] = (bf16_t)p;
    }
}

extern "C" void kernel_launch(void* const* d_in, const int* in_sizes, int n_in,
                              void* d_out, int out_size, void* d_ws, size_t ws_size,
                              hipStream_t stream)
{
    const float* hidden = (const float*)d_in[0];
    const float* W_ih0  = (const float*)d_in[1];
    const float* W_hh0  = (const float*)d_in[2];
    const float* b_ih0  = (const float*)d_in[3];
    const float* b_hh0  = (const float*)d_in[4];
    const float* W_ih1  = (const float*)d_in[5];
    const float* W_hh1  = (const float*)d_in[6];
    const float* b_ih1  = (const float*)d_in[7];
    const float* b_hh1  = (const float*)d_in[8];
    const float* fc1_w  = (const float*)d_in[9];
    const float* fc1_b  = (const float*)d_in[10];
    const float* ln1_g  = (const float*)d_in[11];
    const float* ln1_b  = (const float*)d_in[12];
    const float* fc2_w  = (const float*)d_in[13];
    const float* fc2_b  = (const float*)d_in[14];
    const float* ln2_g  = (const float*)d_in[15];
    const float* ln2_b  = (const float*)d_in[16];
    const float* fc3_w  = (const float*)d_in[17];
    const float* fc3_b  = (const float*)d_in[18];
    float* dout = (float*)d_out;

    char* p = (char*)d_ws;
    auto alloc = [&](size_t bytes) { void* r = (void*)p; p += (bytes + 255) & ~(size_t)255; return r; };
    float*  h0f   = (float*)alloc(262144 * 4);
    float*  h1f   = (float*)alloc(262144 * 4);
    bf16_t* A0[2] = { (bf16_t*)alloc(256 * 1280 * 2), (bf16_t*)alloc(256 * 1280 * 2) };
    bf16_t* A1[2] = { (bf16_t*)alloc(256 * 2048 * 2), (bf16_t*)alloc(256 * 2048 * 2) };
    bf16_t* h1b   = (bf16_t*)alloc(262144 * 2);
    float*  a1r   = (float*)alloc(262144 * 4);
    bf16_t* a1b   = (bf16_t*)alloc(262144 * 2);
    float*  a2r   = (float*)alloc(131072 * 4);
    bf16_t* a2b   = (bf16_t*)alloc(131072 * 2);
    float*  logits= (float*)alloc(65536 * 4);
    float*  b4_0  = (float*)alloc(4096 * 4);
    float*  b4_1  = (float*)alloc(4096 * 4);
    bf16_t* W4_0  = (bf16_t*)alloc((size_t)4096 * 1280 * 2);
    bf16_t* W4_1  = (bf16_t*)alloc((size_t)4096 * 2048 * 2);
    bf16_t* fc1wb = (bf16_t*)alloc((size_t)1048576 * 2);
    bf16_t* fc2wb = (bf16_t*)alloc((size_t)524288 * 2);
    bf16_t* fc3wb = (bf16_t*)alloc((size_t)131072 * 2);

    // weight prep (runs every launch; ~40us total, graph-safe)
    build_w4<<<5120, 256, 0, stream>>>(W_ih0, W_hh0, b_ih0, b_hh0, W4_0, b4_0, 256);
    build_w4<<<8192, 256, 0, stream>>>(W_ih1, W_hh1, b_ih1, b_hh1, W4_1, b4_1, 1024);
    conv_bf16<<<1024, 256, 0, stream>>>(fc1_w, fc1wb);
    conv_bf16<<<512, 256, 0, stream>>>(fc2_w, fc2wb);
    conv_bf16<<<128, 256, 0, stream>>>(fc3_w, fc3wb);
    init_state<<<1024, 256, 0, stream>>>(hidden, h0f, h1f, A0[0], A1[0]);

    for (int t = 0; t < 64; t++) {
        bf16_t* A0r = A0[t & 1];
        bf16_t* A0w = A0[(t + 1) & 1];
        bf16_t* A1r = A1[t & 1];
        bf16_t* A1w = A1[(t + 1) & 1];

        // GRU layer 0: reads A0r=[out|h0], updates h0f, writes bf16 h0 into
        // A1r[:, :1024] (gru1 this step) and A0w[:, 256:1280] (next step).
        gru_gemm<<<dim3(64, 4), 256, 0, stream>>>(
            A0r, W4_0, b4_0, 1280,
            h0f, A1r, 2048, 0, A0w, 1280, 256);
        // GRU layer 1: reads A1r=[h0_new|h1_old], updates h1f, writes bf16 h1
        // into A1w[:, 1024:] (next step) and h1b (fc1 input).
        gru_gemm<<<dim3(64, 4), 256, 0, stream>>>(
            A1r, W4_1, b4_1, 2048,
            h1f, A1w, 2048, 1024, h1b, 1024, 0);
        // FC head
        gemm_mfma<2><<<dim3(16, 8), 128, 0, stream>>>(
            h1b, fc1wb, fc1_b, 1024, a1r, 1024);
        ln_gelu<1024><<<256, 256, 0, stream>>>(a1r, ln1_g, ln1_b, a1b);
        gemm_mfma<2><<<dim3(8, 8), 128, 0, stream>>>(
            a1b, fc2wb, fc2_b, 1024, a2r, 512);
        ln_gelu<512><<<256, 256, 0, stream>>>(a2r, ln2_g, ln2_b, a2b);
        gemm_mfma<2><<<dim3(4, 8), 128, 0, stream>>>(
            a2b, fc3wb, fc3_b, 512, logits, 256);
        softmax_fb<<<64, 256, 0, stream>>>(logits, dout, A0w, t);
    }
}